// Round 8
// baseline (375.303 us; speedup 1.0000x reference)
//
#include <hip/hip_runtime.h>
#include <hip/hip_bf16.h>

// GroupConv2D ABLATION ROUND (R10). Five consecutive failed mechanism predictions
// (R2/R3/R4/R5/R8-9) => stop theorizing, measure phases in isolation (m164-166).
// Correctness: final dispatch = gconv_f32s (R5 kernel, passed at 78us) rewrites
// every output element; earlier dispatches are timing probes only.
//  abl_nostage   : compute+epilogue only (LDS garbage)        -> T_compute+store
//  abl_stage_reg : R5 reg-staging only (load->cvt->ds_write)  -> T_stage_reg
//  abl_stage_dma : fp32 global_load_lds staging only          -> T_stage_dma
//  gconv_dma32   : full DMA-staged fp32 candidate (timing; overwritten)
// Predictions: nostage 30-45, stage_reg 45-60, stage_dma 20-25, dma32 45-60,
// final 78. If stage_dma >> 25: DMA issue path itself is the wall.

#define R_ 4                 // output rows per block-strip

typedef __bf16 bf16x8 __attribute__((ext_vector_type(8)));
typedef float floatx4 __attribute__((ext_vector_type(4)));
typedef unsigned short ushortx4 __attribute__((ext_vector_type(4)));

#define WGT_USHORTS 73728u      // 8*9*32*32
#define ZPAD_USHORTS 64u        // 128B zero pad (OOB DMA target)

__device__ __forceinline__ unsigned short f2bf(float f) {
    unsigned int u = __builtin_bit_cast(unsigned int, f);
    u += 0x7fffu + ((u >> 16) & 1u);           // round-to-nearest-even
    return (unsigned short)(u >> 16);
}

__device__ __forceinline__ bf16x8 cvt_frag(float4 lo, float4 hi) {
    union { bf16x8 v; __hip_bfloat162 h[4]; } u;
    u.h[0] = __float22bfloat162_rn(make_float2(lo.x, lo.y));
    u.h[1] = __float22bfloat162_rn(make_float2(lo.z, lo.w));
    u.h[2] = __float22bfloat162_rn(make_float2(hi.x, hi.y));
    u.h[3] = __float22bfloat162_rn(make_float2(hi.z, hi.w));
    return u.v;
}

// ---- wprep: wgt fp32 [tap][ci][co256] -> bf16 [g][tap][co][ci]; + 128B zero pad
__global__ __launch_bounds__(256)
void wprep(const float* __restrict__ wgt, unsigned short* __restrict__ wbf) {
    const int i = blockIdx.x * 256 + threadIdx.x;
    if (blockIdx.x == 0 && threadIdx.x < ZPAD_USHORTS)
        wbf[WGT_USHORTS + threadIdx.x] = 0;
    const int co256 = i & 255;
    const int tmp   = i >> 8;
    const int ci    = tmp & 31;
    const int kk    = tmp >> 5;
    const int g  = co256 >> 5;
    const int co = co256 & 31;
    wbf[((g * 9 + kk) * 32 + co) * 32 + ci] = f2bf(wgt[i]);
}

// ================= ABLATION A: compute+epilogue, NO staging =================
__global__ __launch_bounds__(256, 7)
void abl_nostage(const unsigned short* __restrict__ wbf,
                 const float* __restrict__ bias, float* __restrict__ out) {
    const int rt = blockIdx.x, g = blockIdx.y, b = blockIdx.z;
    const int y0 = rt * R_;
    __shared__ unsigned short lds_in[6 * 58 * 32];
    const int tid = threadIdx.x;
    if (tid == 0) lds_in[0] = (unsigned short)blockIdx.x;  // defeat undef-fold
    __syncthreads();
    const int wv = tid >> 6, lane = tid & 63, lc = lane & 15, quad = lane >> 4;
    const int nt = (wv < 2) ? 4 : 3;
    const int t0 = (wv < 2) ? (wv * 4) : (8 + (wv - 2) * 3);
    int lane_base[4];
#pragma unroll
    for (int t = 0; t < 4; ++t) {
        const int tt = (t < nt) ? (t0 + t) : 0;
        const int p = tt * 16 + lc;
        const int yl = p / 56;
        lane_base[t] = (yl * 58 + (p - yl * 56)) * 32 + (quad << 3);
    }
    const unsigned short* wq = &wbf[(g * 9 * 32) * 32 + (quad << 3)];
    floatx4 acc[4][2];
#pragma unroll
    for (int t = 0; t < 4; ++t) { acc[t][0] = (floatx4)(0.f); acc[t][1] = (floatx4)(0.f); }
    bf16x8 b0 = *reinterpret_cast<const bf16x8*>(&wq[(0 * 32 + lc) * 32]);
    bf16x8 b1 = *reinterpret_cast<const bf16x8*>(&wq[(0 * 32 + 16 + lc) * 32]);
#pragma unroll
    for (int kk = 0; kk < 9; ++kk) {
        const int koff = ((kk / 3) * 58 + (kk % 3)) * 32;
        bf16x8 nb0 = b0, nb1 = b1;
        if (kk < 8) {
            nb0 = *reinterpret_cast<const bf16x8*>(&wq[((kk + 1) * 32 + lc) * 32]);
            nb1 = *reinterpret_cast<const bf16x8*>(&wq[((kk + 1) * 32 + 16 + lc) * 32]);
        }
#pragma unroll
        for (int t = 0; t < 4; ++t) {
            if (t < nt) {
                const bf16x8 a = *reinterpret_cast<const bf16x8*>(&lds_in[lane_base[t] + koff]);
                acc[t][0] = __builtin_amdgcn_mfma_f32_16x16x32_bf16(b0, a, acc[t][0], 0, 0, 0);
                acc[t][1] = __builtin_amdgcn_mfma_f32_16x16x32_bf16(b1, a, acc[t][1], 0, 0, 0);
            }
        }
        b0 = nb0; b1 = nb1;
    }
    const float4 bv0 = *reinterpret_cast<const float4*>(&bias[(g << 5) + (quad << 2)]);
    const float4 bv1 = *reinterpret_cast<const float4*>(&bias[(g << 5) + 16 + (quad << 2)]);
    const int obase = (((b * 56 + y0) * 56) << 8) + (g << 5) + (quad << 2);
#pragma unroll
    for (int t = 0; t < 4; ++t) {
        if (t < nt) {
            const int p = (t0 + t) * 16 + lc;
            const int y = p / 56, x = p - y * 56;
            float* o = &out[obase + ((y * 56 + x) << 8)];
            float4 s0, s1;
            s0.x = acc[t][0][0] + bv0.x; s0.y = acc[t][0][1] + bv0.y;
            s0.z = acc[t][0][2] + bv0.z; s0.w = acc[t][0][3] + bv0.w;
            s1.x = acc[t][1][0] + bv1.x; s1.y = acc[t][1][1] + bv1.y;
            s1.z = acc[t][1][2] + bv1.z; s1.w = acc[t][1][3] + bv1.w;
            *reinterpret_cast<float4*>(o)      = s0;
            *reinterpret_cast<float4*>(o + 16) = s1;
        }
    }
}

// ================= ABLATION B: R5 reg-staging ONLY =================
__global__ __launch_bounds__(256, 7)
void abl_stage_reg(const float* __restrict__ in) {
    const int rt = blockIdx.x, g = blockIdx.y, b = blockIdx.z;
    const int y0 = rt * R_;
    __shared__ unsigned short lds_in[6 * 58 * 32];
    const int tid = threadIdx.x;
#pragma unroll
    for (int i = 0; i < 11; ++i) {
        const int c = tid + (i << 8);
        if (c < 6 * 58 * 8) {
            const int row = c / 464, rem = c - row * 464, col = rem >> 3, q = rem & 7;
            const int gy = y0 - 1 + row, gx = col - 1;
            float4 v = make_float4(0.f, 0.f, 0.f, 0.f);
            if ((unsigned)gy < 56u && (unsigned)gx < 56u)
                v = *reinterpret_cast<const float4*>(
                    &in[((((b * 56 + gy) * 56 + gx)) << 8) + (g << 5) + (q << 2)]);
            ushortx4 p;
            p.x = f2bf(v.x); p.y = f2bf(v.y); p.z = f2bf(v.z); p.w = f2bf(v.w);
            *reinterpret_cast<ushortx4*>(&lds_in[(row * 58 + col) * 32 + (q << 2)]) = p;
        }
    }
    __syncthreads();
    const int u = (int)lds_in[tid];            // keep LDS live
    asm volatile("" :: "v"(u));
}

// ================= ABLATION C: fp32 DMA staging ONLY =================
// LDS layout [slice 0..351][4 x 32B chunks rotated by slice&3]; dest linear.
__global__ __launch_bounds__(256, 3)
void abl_stage_dma(const float* __restrict__ in, const unsigned short* __restrict__ wbf) {
    const int rt = blockIdx.x, g = blockIdx.y, b = blockIdx.z;
    const int y0 = rt * R_;
    __shared__ float lds[352 * 32];            // 45056 B
    const int tid = threadIdx.x;
    const int wv = tid >> 6, lane = tid & 63;
    const float* zpadf = (const float*)(wbf + WGT_USHORTS);
    for (int i = wv; i < 44; i += 4) {
        const int s    = (i << 3) + (lane >> 3);   // slice 0..351
        const int j16  = lane & 7;
        const int c32d = j16 >> 1;
        const int half = j16 & 1;
        const int c32s = c32d ^ (s & 3);
        const int row  = s / 58;
        const int col  = s - row * 58;
        const int gy   = y0 - 1 + row;
        const int gx   = col - 1;
        const bool ok  = (s < 348) & ((unsigned)gy < 56u) & ((unsigned)gx < 56u);
        const float* src = ok
            ? &in[(((b * 56 + gy) * 56 + gx) << 8) + (g << 5) + (c32s << 3) + (half << 2)]
            : zpadf;
        __builtin_amdgcn_global_load_lds(
            (const __attribute__((address_space(1))) void*)src,
            (__attribute__((address_space(3))) void*)&lds[i << 8],   // i*1024 B
            16, 0, 0);
    }
    __syncthreads();
    const float v = lds[tid];
    asm volatile("" :: "v"(v));
}

// ================= CANDIDATE: full DMA-staged fp32 conv =================
__global__ __launch_bounds__(256, 3)
void gconv_dma32(const float* __restrict__ in, const unsigned short* __restrict__ wbf,
                 const float* __restrict__ bias, float* __restrict__ out) {
    const int rt = blockIdx.x, g = blockIdx.y, b = blockIdx.z;
    const int y0 = rt * R_;
    __shared__ float lds[352 * 32];
    const int tid = threadIdx.x;
    const int wv = tid >> 6, lane = tid & 63;
    const float* zpadf = (const float*)(wbf + WGT_USHORTS);
    for (int i = wv; i < 44; i += 4) {
        const int s    = (i << 3) + (lane >> 3);
        const int j16  = lane & 7;
        const int c32d = j16 >> 1;
        const int half = j16 & 1;
        const int c32s = c32d ^ (s & 3);
        const int row  = s / 58;
        const int col  = s - row * 58;
        const int gy   = y0 - 1 + row;
        const int gx   = col - 1;
        const bool ok  = (s < 348) & ((unsigned)gy < 56u) & ((unsigned)gx < 56u);
        const float* src = ok
            ? &in[(((b * 56 + gy) * 56 + gx) << 8) + (g << 5) + (c32s << 3) + (half << 2)]
            : zpadf;
        __builtin_amdgcn_global_load_lds(
            (const __attribute__((address_space(1))) void*)src,
            (__attribute__((address_space(3))) void*)&lds[i << 8],
            16, 0, 0);
    }
    __syncthreads();   // drains vmcnt -> staging complete

    const int lc = lane & 15, quad = lane >> 4;
    const int nt = (wv < 2) ? 4 : 3;
    const int t0 = (wv < 2) ? (wv * 4) : (8 + (wv - 2) * 3);
    int sbase[4];
#pragma unroll
    for (int t = 0; t < 4; ++t) {
        const int tt = (t < nt) ? (t0 + t) : 0;
        const int p = tt * 16 + lc;
        const int yl = p / 56;
        sbase[t] = yl * 58 + (p - yl * 56);    // halo slice of tap (0,0)
    }
    const unsigned short* wq = &wbf[(g * 9 * 32) * 32 + (quad << 3)];
    floatx4 acc[4][2];
#pragma unroll
    for (int t = 0; t < 4; ++t) { acc[t][0] = (floatx4)(0.f); acc[t][1] = (floatx4)(0.f); }
    bf16x8 b0 = *reinterpret_cast<const bf16x8*>(&wq[(0 * 32 + lc) * 32]);
    bf16x8 b1 = *reinterpret_cast<const bf16x8*>(&wq[(0 * 32 + 16 + lc) * 32]);
#pragma unroll
    for (int kk = 0; kk < 9; ++kk) {
        const int ks = (kk / 3) * 58 + (kk % 3);    // compile-time slice offset
        bf16x8 nb0 = b0, nb1 = b1;
        if (kk < 8) {
            nb0 = *reinterpret_cast<const bf16x8*>(&wq[((kk + 1) * 32 + lc) * 32]);
            nb1 = *reinterpret_cast<const bf16x8*>(&wq[((kk + 1) * 32 + 16 + lc) * 32]);
        }
#pragma unroll
        for (int t = 0; t < 4; ++t) {
            if (t < nt) {
                const int s  = sbase[t] + ks;
                const int fb = (s << 5) + ((quad ^ (s & 3)) << 3);   // float idx
                const float4 lo = *reinterpret_cast<const float4*>(&lds[fb]);
                const float4 hi = *reinterpret_cast<const float4*>(&lds[fb + 4]);
                const bf16x8 a = cvt_frag(lo, hi);
                acc[t][0] = __builtin_amdgcn_mfma_f32_16x16x32_bf16(b0, a, acc[t][0], 0, 0, 0);
                acc[t][1] = __builtin_amdgcn_mfma_f32_16x16x32_bf16(b1, a, acc[t][1], 0, 0, 0);
            }
        }
        b0 = nb0; b1 = nb1;
    }
    const float4 bv0 = *reinterpret_cast<const float4*>(&bias[(g << 5) + (quad << 2)]);
    const float4 bv1 = *reinterpret_cast<const float4*>(&bias[(g << 5) + 16 + (quad << 2)]);
    const int obase = (((b * 56 + y0) * 56) << 8) + (g << 5) + (quad << 2);
#pragma unroll
    for (int t = 0; t < 4; ++t) {
        if (t < nt) {
            const int p = (t0 + t) * 16 + lc;
            const int y = p / 56, x = p - y * 56;
            float* o = &out[obase + ((y * 56 + x) << 8)];
            float4 s0, s1;
            s0.x = acc[t][0][0] + bv0.x; s0.y = acc[t][0][1] + bv0.y;
            s0.z = acc[t][0][2] + bv0.z; s0.w = acc[t][0][3] + bv0.w;
            s1.x = acc[t][1][0] + bv1.x; s1.y = acc[t][1][1] + bv1.y;
            s1.z = acc[t][1][2] + bv1.z; s1.w = acc[t][1][3] + bv1.w;
            *reinterpret_cast<float4*>(o)      = s0;
            *reinterpret_cast<float4*>(o + 16) = s1;
        }
    }
}

// ================= FINAL (correct, R5 kernel, measured 78us) =================
__global__ __launch_bounds__(256, 7)
void gconv_f32s(const float* __restrict__ in, const unsigned short* __restrict__ wbf,
                const float* __restrict__ bias, float* __restrict__ out) {
    const int rt = blockIdx.x, g = blockIdx.y, b = blockIdx.z;
    const int y0 = rt * R_;
    __shared__ unsigned short lds_in[6 * 58 * 32];
    const int tid = threadIdx.x;
#pragma unroll
    for (int i = 0; i < 11; ++i) {
        const int c = tid + (i << 8);
        if (c < 6 * 58 * 8) {
            const int row = c / 464, rem = c - row * 464, col = rem >> 3, q = rem & 7;
            const int gy = y0 - 1 + row, gx = col - 1;
            float4 v = make_float4(0.f, 0.f, 0.f, 0.f);
            if ((unsigned)gy < 56u && (unsigned)gx < 56u)
                v = *reinterpret_cast<const float4*>(
                    &in[((((b * 56 + gy) * 56 + gx)) << 8) + (g << 5) + (q << 2)]);
            ushortx4 p;
            p.x = f2bf(v.x); p.y = f2bf(v.y); p.z = f2bf(v.z); p.w = f2bf(v.w);
            *reinterpret_cast<ushortx4*>(&lds_in[(row * 58 + col) * 32 + (q << 2)]) = p;
        }
    }
    __syncthreads();
    const int wv = tid >> 6, lane = tid & 63, lc = lane & 15, quad = lane >> 4;
    const int nt = (wv < 2) ? 4 : 3;
    const int t0 = (wv < 2) ? (wv * 4) : (8 + (wv - 2) * 3);
    int lane_base[4];
#pragma unroll
    for (int t = 0; t < 4; ++t) {
        const int tt = (t < nt) ? (t0 + t) : 0;
        const int p = tt * 16 + lc;
        const int yl = p / 56;
        lane_base[t] = (yl * 58 + (p - yl * 56)) * 32 + (quad << 3);
    }
    const unsigned short* wq = &wbf[(g * 9 * 32) * 32 + (quad << 3)];
    floatx4 acc[4][2];
#pragma unroll
    for (int t = 0; t < 4; ++t) { acc[t][0] = (floatx4)(0.f); acc[t][1] = (floatx4)(0.f); }
    bf16x8 b0 = *reinterpret_cast<const bf16x8*>(&wq[(0 * 32 + lc) * 32]);
    bf16x8 b1 = *reinterpret_cast<const bf16x8*>(&wq[(0 * 32 + 16 + lc) * 32]);
#pragma unroll
    for (int kk = 0; kk < 9; ++kk) {
        const int koff = ((kk / 3) * 58 + (kk % 3)) * 32;
        bf16x8 nb0 = b0, nb1 = b1;
        if (kk < 8) {
            nb0 = *reinterpret_cast<const bf16x8*>(&wq[((kk + 1) * 32 + lc) * 32]);
            nb1 = *reinterpret_cast<const bf16x8*>(&wq[((kk + 1) * 32 + 16 + lc) * 32]);
        }
#pragma unroll
        for (int t = 0; t < 4; ++t) {
            if (t < nt) {
                const bf16x8 a = *reinterpret_cast<const bf16x8*>(&lds_in[lane_base[t] + koff]);
                acc[t][0] = __builtin_amdgcn_mfma_f32_16x16x32_bf16(b0, a, acc[t][0], 0, 0, 0);
                acc[t][1] = __builtin_amdgcn_mfma_f32_16x16x32_bf16(b1, a, acc[t][1], 0, 0, 0);
            }
        }
        b0 = nb0; b1 = nb1;
    }
    const float4 bv0 = *reinterpret_cast<const float4*>(&bias[(g << 5) + (quad << 2)]);
    const float4 bv1 = *reinterpret_cast<const float4*>(&bias[(g << 5) + 16 + (quad << 2)]);
    const int obase = (((b * 56 + y0) * 56) << 8) + (g << 5) + (quad << 2);
#pragma unroll
    for (int t = 0; t < 4; ++t) {
        if (t < nt) {
            const int p = (t0 + t) * 16 + lc;
            const int y = p / 56, x = p - y * 56;
            float* o = &out[obase + ((y * 56 + x) << 8)];
            float4 s0, s1;
            s0.x = acc[t][0][0] + bv0.x; s0.y = acc[t][0][1] + bv0.y;
            s0.z = acc[t][0][2] + bv0.z; s0.w = acc[t][0][3] + bv0.w;
            s1.x = acc[t][1][0] + bv1.x; s1.y = acc[t][1][1] + bv1.y;
            s1.z = acc[t][1][2] + bv1.z; s1.w = acc[t][1][3] + bv1.w;
            *reinterpret_cast<float4*>(o)      = s0;
            *reinterpret_cast<float4*>(o + 16) = s1;
        }
    }
}

// ---- last-resort fallback (round-1 kernel, no workspace) ----
__global__ __launch_bounds__(256, 2)
void gconv_mfma_ldsw(const float* __restrict__ in, const float* __restrict__ wgt,
                     const float* __restrict__ bias, float* __restrict__ out) {
    const int rt = blockIdx.x, g = blockIdx.y, b = blockIdx.z;
    const int y0 = rt * 8;
    __shared__ unsigned short lds_in[10 * 58 * 32];
    __shared__ unsigned short lds_w[9 * 32 * 32];
    const int tid = threadIdx.x;
    for (int i = tid; i < 9 * 32 * 32; i += 256) {
        const int co = i & 31, ci = (i >> 5) & 31, kk = i >> 10;
        lds_w[(kk * 32 + co) * 32 + ci] = f2bf(wgt[(kk * 32 + ci) * 256 + g * 32 + co]);
    }
    for (int c = tid; c < 10 * 58 * 8; c += 256) {
        const int row = c / 464, rem = c - row * 464, col = rem >> 3, q = rem & 7;
        const int gy = y0 - 1 + row, gx = col - 1;
        float4 v = make_float4(0.f, 0.f, 0.f, 0.f);
        if ((unsigned)gy < 56u && (unsigned)gx < 56u)
            v = *reinterpret_cast<const float4*>(&in[(((b * 56 + gy) * 56 + gx) * 256) + g * 32 + q * 4]);
        ushortx4 p;
        p.x = f2bf(v.x); p.y = f2bf(v.y); p.z = f2bf(v.z); p.w = f2bf(v.w);
        *reinterpret_cast<ushortx4*>(&lds_in[(row * 58 + col) * 32 + q * 4]) = p;
    }
    __syncthreads();
    const int wv = tid >> 6, lane = tid & 63, lc = lane & 15, quad = lane >> 4;
    int lane_base[7];
#pragma unroll
    for (int t = 0; t < 7; ++t) {
        const int p = (wv * 7 + t) * 16 + lc;
        const int yl = p / 56, xl = p - yl * 56;
        lane_base[t] = (yl * 58 + xl) * 32 + quad * 8;
    }
    floatx4 acc[7][2];
#pragma unroll
    for (int t = 0; t < 7; ++t) { acc[t][0] = (floatx4)(0.f); acc[t][1] = (floatx4)(0.f); }
#pragma unroll
    for (int kk = 0; kk < 9; ++kk) {
        const int ky = kk / 3, kx = kk % 3;
        const int koff = (ky * 58 + kx) * 32;
        const bf16x8 bf0 = *reinterpret_cast<const bf16x8*>(&lds_w[(kk * 32 + lc) * 32 + quad * 8]);
        const bf16x8 bf1 = *reinterpret_cast<const bf16x8*>(&lds_w[(kk * 32 + 16 + lc) * 32 + quad * 8]);
#pragma unroll
        for (int t = 0; t < 7; ++t) {
            const bf16x8 a = *reinterpret_cast<const bf16x8*>(&lds_in[lane_base[t] + koff]);
            acc[t][0] = __builtin_amdgcn_mfma_f32_16x16x32_bf16(a, bf0, acc[t][0], 0, 0, 0);
            acc[t][1] = __builtin_amdgcn_mfma_f32_16x16x32_bf16(a, bf1, acc[t][1], 0, 0, 0);
        }
    }
    const float bv0 = bias[g * 32 + lc], bv1 = bias[g * 32 + 16 + lc];
#pragma unroll
    for (int t = 0; t < 7; ++t)
#pragma unroll
        for (int r = 0; r < 4; ++r) {
            const int p = (wv * 7 + t) * 16 + quad * 4 + r;
            const int y = p / 56, x = p - y * 56;
            float* o = &out[(((b * 56) + y0 + y) * 56 + x) * 256 + g * 32];
            o[lc] = acc[t][0][r] + bv0;
            o[16 + lc] = acc[t][1][r] + bv1;
        }
}

extern "C" void kernel_launch(void* const* d_in, const int* in_sizes, int n_in,
                              void* d_out, int out_size, void* d_ws, size_t ws_size,
                              hipStream_t stream) {
    const float* in   = (const float*)d_in[0];
    const float* wgt  = (const float*)d_in[1];
    const float* bias = (const float*)d_in[2];
    float* out        = (float*)d_out;

    const size_t need_wgt = (size_t)(WGT_USHORTS + ZPAD_USHORTS) * 2;

    if (d_ws != nullptr && ws_size >= need_wgt) {
        unsigned short* wbf = (unsigned short*)d_ws;
        const dim3 grid(14, 8, 32), blk(256, 1, 1);
        wprep<<<dim3(288, 1, 1), blk, 0, stream>>>(wgt, wbf);
        abl_nostage  <<<grid, blk, 0, stream>>>(wbf, bias, out);   // garbage, overwritten
        abl_stage_reg<<<grid, blk, 0, stream>>>(in);
        abl_stage_dma<<<grid, blk, 0, stream>>>(in, wbf);
        gconv_dma32  <<<grid, blk, 0, stream>>>(in, wbf, bias, out); // timing probe
        gconv_f32s   <<<grid, blk, 0, stream>>>(in, wbf, bias, out); // correct final
    } else {
        gconv_mfma_ldsw<<<dim3(7, 8, 32), dim3(256, 1, 1), 0, stream>>>(in, wgt, bias, out);
    }
}